// Round 15
// baseline (506.702 us; speedup 1.0000x reference)
//
#include <hip/hip_runtime.h>

#define N_NODES 100000
#define N_EDGES 1600000
#define IN_CH 128
#define HID 64
#define OUT_CH 16
#define N_GRAPHS 512
#define NEG_SLOPE 0.2f

#define MAX_DEG 64  // scatter slots; gat uses first 63 (Poisson(16): P(deg>63) ~ 1e-14)

#define GEMM1_BLOCKS ((N_NODES + 127) / 128)               // 782
#define DEG_EPT 8
#define DEG_BLOCKS ((N_EDGES + 256 * DEG_EPT - 1) / (256 * DEG_EPT))  // 782
#define FUSED_BLOCKS (GEMM1_BLOCKS + DEG_BLOCKS)           // 1564

#define NEG_BIG (-1e30f)
#define LDSP 132  // 128 + 4: bank stride 4 mod 32, keeps 16B alignment

// bf16 helpers (round-to-nearest-even)
__device__ __forceinline__ unsigned int f2bf_pack(float lo, float hi) {
  unsigned int ul = __float_as_uint(lo);
  unsigned int uh = __float_as_uint(hi);
  ul = (ul + 0x7FFFu + ((ul >> 16) & 1u)) >> 16;
  uh = (uh + 0x7FFFu + ((uh >> 16) & 1u)) >> 16;
  return ul | (uh << 16);
}
__device__ __forceinline__ float bf2f(unsigned short b) {
  return __uint_as_float(((unsigned int)b) << 16);
}
// unpack packed bf16 pair from one int
__device__ __forceinline__ float bfu_lo(int u) {
  return __uint_as_float(((unsigned int)u) << 16);
}
__device__ __forceinline__ float bfu_hi(int u) {
  return __uint_as_float(((unsigned int)u) & 0xFFFF0000u);
}

// ---------------- fused: layer-1 dual GEMM + one-pass padded-CSR scatter ----------------

__global__ __launch_bounds__(256) void k_fused_gemm1_scatter(
    const float* __restrict__ x,
    const float* __restrict__ Wl, const float* __restrict__ bl,
    const float* __restrict__ Wr, const float* __restrict__ br,
    unsigned short* __restrict__ xlb, unsigned short* __restrict__ xrb,
    const int* __restrict__ src, const int* __restrict__ dst,
    int* __restrict__ deg, int* __restrict__ adjP) {
  constexpr int K = IN_CH;
  constexpr int KC = 16;
  constexpr int NCH = K / KC;  // 8
  __shared__ float xs[KC][LDSP];
  __shared__ float ws[KC][LDSP];

  int b = blockIdx.x;
  if (b & 1) {
    int db = b >> 1;
    int base = (db * 256 + threadIdx.x) * DEG_EPT;
    if (base + DEG_EPT <= N_EDGES) {
      int4 d4a = *(const int4*)&dst[base];
      int4 d4b = *(const int4*)&dst[base + 4];
      int4 s4a = *(const int4*)&src[base];
      int4 s4b = *(const int4*)&src[base + 4];
      int sl;
      sl = atomicAdd(&deg[d4a.x], 1); if (sl < MAX_DEG) adjP[d4a.x * MAX_DEG + sl] = s4a.x;
      sl = atomicAdd(&deg[d4a.y], 1); if (sl < MAX_DEG) adjP[d4a.y * MAX_DEG + sl] = s4a.y;
      sl = atomicAdd(&deg[d4a.z], 1); if (sl < MAX_DEG) adjP[d4a.z * MAX_DEG + sl] = s4a.z;
      sl = atomicAdd(&deg[d4a.w], 1); if (sl < MAX_DEG) adjP[d4a.w * MAX_DEG + sl] = s4a.w;
      sl = atomicAdd(&deg[d4b.x], 1); if (sl < MAX_DEG) adjP[d4b.x * MAX_DEG + sl] = s4b.x;
      sl = atomicAdd(&deg[d4b.y], 1); if (sl < MAX_DEG) adjP[d4b.y * MAX_DEG + sl] = s4b.y;
      sl = atomicAdd(&deg[d4b.z], 1); if (sl < MAX_DEG) adjP[d4b.z * MAX_DEG + sl] = s4b.z;
      sl = atomicAdd(&deg[d4b.w], 1); if (sl < MAX_DEG) adjP[d4b.w * MAX_DEG + sl] = s4b.w;
    } else {
      for (int e = base; e < N_EDGES; e++) {
        int d = dst[e];
        int sl = atomicAdd(&deg[d], 1);
        if (sl < MAX_DEG) adjP[d * MAX_DEG + sl] = src[e];
      }
    }
    return;
  }

  int tid = threadIdx.x;
  int tx = tid & 15;
  int ty = tid >> 4;
  int nb = (b >> 1) * 128;

  float acc[8][8];
  #pragma unroll
  for (int i = 0; i < 8; i++)
    #pragma unroll
    for (int j = 0; j < 8; j++) acc[i][j] = 0.f;

  for (int c = 0; c < NCH; c++) {
    int kc = c * KC;
    if (c) __syncthreads();
    #pragma unroll
    for (int j = 0; j < 2; j++) {
      int idx = tid + 256 * j;
      int node = idx >> 2, q = idx & 3;
      int gn = nb + node;
      float4 v = make_float4(0.f, 0.f, 0.f, 0.f);
      if (gn < N_NODES) v = *(const float4*)&x[(size_t)gn * K + kc + q * 4];
      xs[q * 4 + 0][node] = v.x;
      xs[q * 4 + 1][node] = v.y;
      xs[q * 4 + 2][node] = v.z;
      xs[q * 4 + 3][node] = v.w;
    }
    #pragma unroll
    for (int j = 0; j < 2; j++) {
      int idx = tid + 256 * j;
      int k = idx >> 5, cc = idx & 31;
      float4 v;
      if (cc < 16) v = *(const float4*)&Wl[(size_t)(kc + k) * 64 + cc * 4];
      else         v = *(const float4*)&Wr[(size_t)(kc + k) * 64 + (cc - 16) * 4];
      *(float4*)&ws[k][cc * 4] = v;
    }
    __syncthreads();

    #pragma unroll 4
    for (int k = 0; k < KC; k++) {
      float4 a0 = *(const float4*)&xs[k][ty * 8];
      float4 a1 = *(const float4*)&xs[k][ty * 8 + 4];
      float4 b0 = *(const float4*)&ws[k][tx * 8];
      float4 b1 = *(const float4*)&ws[k][tx * 8 + 4];
      float av[8] = {a0.x, a0.y, a0.z, a0.w, a1.x, a1.y, a1.z, a1.w};
      float bv[8] = {b0.x, b0.y, b0.z, b0.w, b1.x, b1.y, b1.z, b1.w};
      #pragma unroll
      for (int i = 0; i < 8; i++)
        #pragma unroll
        for (int j = 0; j < 8; j++)
          acc[i][j] = fmaf(av[i], bv[j], acc[i][j]);
    }
  }

  int f0 = tx * 8;
  float bb[8];
  #pragma unroll
  for (int j = 0; j < 8; j++)
    bb[j] = (f0 < 64) ? bl[f0 + j] : br[f0 - 64 + j];
  unsigned short* outp = (f0 < 64) ? xlb : xrb;
  int fo = (f0 < 64) ? f0 : f0 - 64;
  #pragma unroll
  for (int i = 0; i < 8; i++) {
    int node = nb + ty * 8 + i;
    if (node < N_NODES) {
      int4 o;
      o.x = (int)f2bf_pack(acc[i][0] + bb[0], acc[i][1] + bb[1]);
      o.y = (int)f2bf_pack(acc[i][2] + bb[2], acc[i][3] + bb[3]);
      o.z = (int)f2bf_pack(acc[i][4] + bb[4], acc[i][5] + bb[5]);
      o.w = (int)f2bf_pack(acc[i][6] + bb[6], acc[i][7] + bb[7]);
      *(int4*)&outp[(size_t)node * 64 + fo] = o;
    }
  }
}

// ---------------- layer-2 dual GEMM (fp32 in, bf16 out) ----------------

template <int K>
__global__ __launch_bounds__(256) void k_dual_gemm(
    const float* __restrict__ x,
    const float* __restrict__ Wl, const float* __restrict__ bl,
    const float* __restrict__ Wr, const float* __restrict__ br,
    unsigned short* __restrict__ xlb, unsigned short* __restrict__ xrb) {
  constexpr int KC = 32;
  constexpr int NCH = K / KC;
  __shared__ float xs[KC][LDSP];
  __shared__ float ws[KC][LDSP];

  int tid = threadIdx.x;
  int tx = tid & 15;
  int ty = tid >> 4;
  int nb = blockIdx.x * 128;

  float acc[8][8];
  #pragma unroll
  for (int i = 0; i < 8; i++)
    #pragma unroll
    for (int j = 0; j < 8; j++) acc[i][j] = 0.f;

  for (int c = 0; c < NCH; c++) {
    int kc = c * KC;
    if (c) __syncthreads();
    #pragma unroll
    for (int j = 0; j < 4; j++) {
      int idx = tid + 256 * j;
      int node = idx >> 3, q = idx & 7;
      int gn = nb + node;
      float4 v = make_float4(0.f, 0.f, 0.f, 0.f);
      if (gn < N_NODES) v = *(const float4*)&x[(size_t)gn * K + kc + q * 4];
      xs[q * 4 + 0][node] = v.x;
      xs[q * 4 + 1][node] = v.y;
      xs[q * 4 + 2][node] = v.z;
      xs[q * 4 + 3][node] = v.w;
    }
    #pragma unroll
    for (int j = 0; j < 4; j++) {
      int idx = tid + 256 * j;
      int k = idx >> 5, cc = idx & 31;
      float4 v;
      if (cc < 16) v = *(const float4*)&Wl[(size_t)(kc + k) * 64 + cc * 4];
      else         v = *(const float4*)&Wr[(size_t)(kc + k) * 64 + (cc - 16) * 4];
      *(float4*)&ws[k][cc * 4] = v;
    }
    __syncthreads();

    #pragma unroll 4
    for (int k = 0; k < KC; k++) {
      float4 a0 = *(const float4*)&xs[k][ty * 8];
      float4 a1 = *(const float4*)&xs[k][ty * 8 + 4];
      float4 b0 = *(const float4*)&ws[k][tx * 8];
      float4 b1 = *(const float4*)&ws[k][tx * 8 + 4];
      float av[8] = {a0.x, a0.y, a0.z, a0.w, a1.x, a1.y, a1.z, a1.w};
      float bv[8] = {b0.x, b0.y, b0.z, b0.w, b1.x, b1.y, b1.z, b1.w};
      #pragma unroll
      for (int i = 0; i < 8; i++)
        #pragma unroll
        for (int j = 0; j < 8; j++)
          acc[i][j] = fmaf(av[i], bv[j], acc[i][j]);
    }
  }

  int f0 = tx * 8;
  float bb[8];
  #pragma unroll
  for (int j = 0; j < 8; j++)
    bb[j] = (f0 < 64) ? bl[f0 + j] : br[f0 - 64 + j];
  unsigned short* outp = (f0 < 64) ? xlb : xrb;
  int fo = (f0 < 64) ? f0 : f0 - 64;
  #pragma unroll
  for (int i = 0; i < 8; i++) {
    int node = nb + ty * 8 + i;
    if (node < N_NODES) {
      int4 o;
      o.x = (int)f2bf_pack(acc[i][0] + bb[0], acc[i][1] + bb[1]);
      o.y = (int)f2bf_pack(acc[i][2] + bb[2], acc[i][3] + bb[3]);
      o.z = (int)f2bf_pack(acc[i][4] + bb[4], acc[i][5] + bb[5]);
      o.w = (int)f2bf_pack(acc[i][6] + bb[6], acc[i][7] + bb[7]);
      *(int4*)&outp[(size_t)node * 64 + fo] = o;
    }
  }
}

// ---------------- GATv2 layer: two-phase exact softmax (deg <= 63 fits in wave) ----------------
// Phase 1: lane q = {self, edges}; per-lane 64-feat score via 8 independent 16 B
//   row loads (xr/att are wave-uniform -> SALU); 6-step max + exp + 6-step sum.
// Phase 2: sub(2b)/fg(4b) layout weighted gather-sum — NO online rescale, so all
//   rounds' gathers are independent (full MLP in flight); plain-add sub merge.

__global__ __launch_bounds__(256) void k_gat(
    const unsigned short* __restrict__ xlb, const unsigned short* __restrict__ xrb,
    const float* __restrict__ att, const float* __restrict__ bias,
    const int* __restrict__ deg, const int* __restrict__ adjP,
    float* __restrict__ out, int do_relu) {
  int wid = (blockIdx.x * 256 + threadIdx.x) >> 6;
  int lane = threadIdx.x & 63;
  if (wid >= N_NODES) return;

  int degv = deg[wid];
  degv = (degv < 63) ? degv : 63;
  int L = degv + 1;  // q=0: self-loop, q=1..degv: edges; L <= 64

  // lane q holds neighbor index j_q
  int j = wid;
  if (lane >= 1 && lane <= degv) j = adjP[(size_t)wid * MAX_DEG + (lane - 1)];

  // ---- phase 1: per-lane score over all 64 features ----
  float s0 = 0.f, s1 = 0.f, s2 = 0.f, s3 = 0.f;
  if (lane < L) {
    const unsigned short* row = &xlb[(size_t)j * 64];
    #pragma unroll
    for (int c = 0; c < 8; c++) {
      int4 raw = *(const int4*)&row[c * 8];                         // this edge's 8 feats
      int4 xrr = *(const int4*)&xrb[(size_t)wid * 64 + c * 8];      // wave-uniform
      float4 a0 = *(const float4*)&att[c * 8];                      // wave-uniform
      float4 a1 = *(const float4*)&att[c * 8 + 4];
      float h;
      h = bfu_lo(raw.x) + bfu_lo(xrr.x); h = (h >= 0.f) ? h : NEG_SLOPE * h; s0 = fmaf(h, a0.x, s0);
      h = bfu_hi(raw.x) + bfu_hi(xrr.x); h = (h >= 0.f) ? h : NEG_SLOPE * h; s1 = fmaf(h, a0.y, s1);
      h = bfu_lo(raw.y) + bfu_lo(xrr.y); h = (h >= 0.f) ? h : NEG_SLOPE * h; s2 = fmaf(h, a0.z, s2);
      h = bfu_hi(raw.y) + bfu_hi(xrr.y); h = (h >= 0.f) ? h : NEG_SLOPE * h; s3 = fmaf(h, a0.w, s3);
      h = bfu_lo(raw.z) + bfu_lo(xrr.z); h = (h >= 0.f) ? h : NEG_SLOPE * h; s0 = fmaf(h, a1.x, s0);
      h = bfu_hi(raw.z) + bfu_hi(xrr.z); h = (h >= 0.f) ? h : NEG_SLOPE * h; s1 = fmaf(h, a1.y, s1);
      h = bfu_lo(raw.w) + bfu_lo(xrr.w); h = (h >= 0.f) ? h : NEG_SLOPE * h; s2 = fmaf(h, a1.z, s2);
      h = bfu_hi(raw.w) + bfu_hi(xrr.w); h = (h >= 0.f) ? h : NEG_SLOPE * h; s3 = fmaf(h, a1.w, s3);
    }
  }
  float e = (lane < L) ? ((s0 + s1) + (s2 + s3)) : NEG_BIG;

  float m = e;
  #pragma unroll
  for (int o = 1; o < 64; o <<= 1) m = fmaxf(m, __shfl_xor(m, o, 64));
  float w = __expf(e - m);  // inactive lanes: exp(NEG_BIG - m) = 0
  float z = w;
  #pragma unroll
  for (int o = 1; o < 64; o <<= 1) z += __shfl_xor(z, o, 64);

  // ---- phase 2: weighted gather-sum (independent rounds) ----
  int fg = lane & 15;
  int sub = lane >> 4;
  float4 acc = make_float4(0.f, 0.f, 0.f, 0.f);
  for (int p0 = 0; p0 < L; p0 += 8) {
    int q0 = p0 + sub * 2;
    int q1 = q0 + 1;
    float w0 = __shfl(w, q0 & 63, 64);
    float w1 = __shfl(w, q1 & 63, 64);
    int j0 = __shfl(j, q0 & 63, 64);
    int j1 = __shfl(j, q1 & 63, 64);
    if (q0 < L) {
      ushort4 r = *(const ushort4*)&xlb[(size_t)j0 * 64 + fg * 4];
      acc.x = fmaf(w0, bf2f(r.x), acc.x);
      acc.y = fmaf(w0, bf2f(r.y), acc.y);
      acc.z = fmaf(w0, bf2f(r.z), acc.z);
      acc.w = fmaf(w0, bf2f(r.w), acc.w);
    }
    if (q1 < L) {
      ushort4 r = *(const ushort4*)&xlb[(size_t)j1 * 64 + fg * 4];
      acc.x = fmaf(w1, bf2f(r.x), acc.x);
      acc.y = fmaf(w1, bf2f(r.y), acc.y);
      acc.z = fmaf(w1, bf2f(r.z), acc.z);
      acc.w = fmaf(w1, bf2f(r.w), acc.w);
    }
  }

  // merge the 4 subgroup partials (plain adds — weights already final)
  #pragma unroll
  for (int o = 16; o <= 32; o <<= 1) {
    acc.x += __shfl_xor(acc.x, o, 64);
    acc.y += __shfl_xor(acc.y, o, 64);
    acc.z += __shfl_xor(acc.z, o, 64);
    acc.w += __shfl_xor(acc.w, o, 64);
  }

  if (sub == 0) {
    float4 b4 = *(const float4*)&bias[fg * 4];
    float inv = 1.f / z;
    float4 r;
    r.x = acc.x * inv + b4.x;
    r.y = acc.y * inv + b4.y;
    r.z = acc.z * inv + b4.z;
    r.w = acc.w * inv + b4.w;
    if (do_relu) {
      r.x = fmaxf(r.x, 0.f); r.y = fmaxf(r.y, 0.f);
      r.z = fmaxf(r.z, 0.f); r.w = fmaxf(r.w, 0.f);
    }
    *(float4*)&out[(size_t)wid * 64 + fg * 4] = r;
  }
}

// ---------------- global mean pool (batch is sorted) ----------------

__device__ __forceinline__ int lower_bound_batch(const int* __restrict__ b, int key) {
  int lo = 0, hi = N_NODES;
  while (lo < hi) {
    int mid = (lo + hi) >> 1;
    if (b[mid] < key) lo = mid + 1; else hi = mid;
  }
  return lo;
}

__global__ void k_pool(const float* __restrict__ h, const int* __restrict__ batch,
                       float* __restrict__ gmean) {
  __shared__ int s_range[2];
  __shared__ float red[256];
  int g = blockIdx.x, t = threadIdx.x;
  if (t == 0) s_range[0] = lower_bound_batch(batch, g);
  if (t == 1) s_range[1] = lower_bound_batch(batch, g + 1);
  __syncthreads();
  int lo = s_range[0], hi = s_range[1];
  int f = t & 63, sub = t >> 6;
  float acc = 0.f;
  for (int n = lo + sub; n < hi; n += 4) acc += h[n * 64 + f];
  red[t] = acc;
  __syncthreads();
  if (sub == 0) {
    float s = red[f] + red[64 + f] + red[128 + f] + red[192 + f];
    int cnt = hi - lo;
    if (cnt < 1) cnt = 1;
    gmean[g * 64 + f] = s / (float)cnt;
  }
}

// ---------------- MLP head (separate small kernels) ----------------

__global__ void k_head1(const float* __restrict__ gmean, const float* __restrict__ W,
                        const float* __restrict__ b, float* __restrict__ y) {
  int idx = blockIdx.x * 256 + threadIdx.x;
  if (idx >= N_GRAPHS * 64) return;
  int gi = idx >> 6, f = idx & 63;
  float acc = b[f];
  #pragma unroll 8
  for (int k = 0; k < 64; k++) acc = fmaf(gmean[gi * 64 + k], W[k * 64 + f], acc);
  y[idx] = acc;
}

__global__ void k_bnstats(const float* __restrict__ y, float* __restrict__ mu,
                          float* __restrict__ rstd) {
  __shared__ float red_s[256], red_ss[256];
  int t = threadIdx.x;
  int f = t & 63, grp = t >> 6;
  float s = 0.f, ss = 0.f;
  for (int g = grp; g < N_GRAPHS; g += 4) {
    float v = y[g * 64 + f];
    s += v;
    ss += v * v;
  }
  red_s[t] = s;
  red_ss[t] = ss;
  __syncthreads();
  if (t < 64) {
    s = red_s[t] + red_s[64 + t] + red_s[128 + t] + red_s[192 + t];
    ss = red_ss[t] + red_ss[64 + t] + red_ss[128 + t] + red_ss[192 + t];
    float m = s / (float)N_GRAPHS;
    float var = ss / (float)N_GRAPHS - m * m;
    mu[t] = m;
    rstd[t] = rsqrtf(var + 1e-5f);
  }
}

__global__ void k_head2(const float* __restrict__ y, const float* __restrict__ gamma,
                        const float* __restrict__ beta, const float* __restrict__ mu,
                        const float* __restrict__ rstd, const float* __restrict__ W2,
                        const float* __restrict__ b2, float* __restrict__ out) {
  int idx = blockIdx.x * 256 + threadIdx.x;
  if (idx >= N_GRAPHS * OUT_CH) return;
  int gi = idx >> 4, o = idx & 15;
  float acc = b2[o];
  #pragma unroll
  for (int k = 0; k < 64; k++) {
    float v = y[gi * 64 + k];
    v = gamma[k] * (v - mu[k]) * rstd[k] + beta[k];
    v = fmaxf(v, 0.f);
    acc = fmaf(v, W2[k * OUT_CH + o], acc);
  }
  float mx = acc;
  #pragma unroll
  for (int w = 8; w > 0; w >>= 1) mx = fmaxf(mx, __shfl_xor(mx, w, 16));
  float ex = __expf(acc - mx);
  float s = ex;
  #pragma unroll
  for (int w = 8; w > 0; w >>= 1) s += __shfl_xor(s, w, 16);
  out[idx] = acc - mx - __logf(s);
}

// ---------------- launcher ----------------
// ws budget identical to R11 (proven): deg 0.4 + adjP 25.6 + xlb 12.8 +
// xrb 12.8 + h 25.6 + small ~0.3 = ~77.5 MB.

extern "C" void kernel_launch(void* const* d_in, const int* in_sizes, int n_in,
                              void* d_out, int out_size, void* d_ws, size_t ws_size,
                              hipStream_t stream) {
  const float* x      = (const float*)d_in[0];
  const int*   edge   = (const int*)d_in[1];
  const int*   batch  = (const int*)d_in[2];
  const float* W_l1   = (const float*)d_in[3];
  const float* b_l1   = (const float*)d_in[4];
  const float* W_r1   = (const float*)d_in[5];
  const float* b_r1   = (const float*)d_in[6];
  const float* att1   = (const float*)d_in[7];
  const float* bias1  = (const float*)d_in[8];
  const float* W_l2   = (const float*)d_in[9];
  const float* b_l2   = (const float*)d_in[10];
  const float* W_r2   = (const float*)d_in[11];
  const float* b_r2   = (const float*)d_in[12];
  const float* att2   = (const float*)d_in[13];
  const float* bias2  = (const float*)d_in[14];
  const float* W_fc1  = (const float*)d_in[15];
  const float* b_fc1  = (const float*)d_in[16];
  const float* gamma  = (const float*)d_in[17];
  const float* beta   = (const float*)d_in[18];
  const float* W_fc2  = (const float*)d_in[19];
  const float* b_fc2  = (const float*)d_in[20];

  const int* src = edge;
  const int* dst = edge + N_EDGES;

  char* ws = (char*)d_ws;
  size_t off = 0;
  auto alloc = [&](size_t bytes) -> void* {
    off = (off + 255) & ~(size_t)255;
    void* p = ws + off;
    off += bytes;
    return p;
  };
  int* deg      = (int*)alloc((size_t)N_NODES * 4);
  int* adjP     = (int*)alloc((size_t)N_NODES * MAX_DEG * 4);
  unsigned short* xlb = (unsigned short*)alloc((size_t)N_NODES * HID * 2);
  unsigned short* xrb = (unsigned short*)alloc((size_t)N_NODES * HID * 2);
  float* h      = (float*)alloc((size_t)N_NODES * HID * 4);
  float* gmean  = (float*)alloc((size_t)N_GRAPHS * HID * 4);
  float* y      = (float*)alloc((size_t)N_GRAPHS * HID * 4);
  float* mu     = (float*)alloc(64 * 4);
  float* rstd   = (float*)alloc(64 * 4);

  hipMemsetAsync(deg, 0, (size_t)N_NODES * 4, stream);

  k_fused_gemm1_scatter<<<FUSED_BLOCKS, 256, 0, stream>>>(
      x, W_l1, b_l1, W_r1, b_r1, xlb, xrb, src, dst, deg, adjP);

  k_gat<<<(N_NODES + 3) / 4, 256, 0, stream>>>(xlb, xrb, att1, bias1, deg, adjP, h, 1);
  k_dual_gemm<HID><<<(N_NODES + 127) / 128, 256, 0, stream>>>(h, W_l2, b_l2, W_r2, b_r2, xlb, xrb);
  k_gat<<<(N_NODES + 3) / 4, 256, 0, stream>>>(xlb, xrb, att2, bias2, deg, adjP, h, 0);

  k_pool<<<N_GRAPHS, 256, 0, stream>>>(h, batch, gmean);
  k_head1<<<(N_GRAPHS * 64 + 255) / 256, 256, 0, stream>>>(gmean, W_fc1, b_fc1, y);
  k_bnstats<<<1, 256, 0, stream>>>(y, mu, rstd);
  k_head2<<<(N_GRAPHS * OUT_CH + 255) / 256, 256, 0, stream>>>(y, gamma, beta, mu, rstd,
                                                               W_fc2, b_fc2, (float*)d_out);
}

// Round 16
// 434.196 us; speedup vs baseline: 1.1670x; 1.1670x over previous
//
#include <hip/hip_runtime.h>

#define N_NODES 100000
#define N_EDGES 1600000
#define IN_CH 128
#define HID 64
#define OUT_CH 16
#define N_GRAPHS 512
#define NEG_SLOPE 0.2f

#define MAX_DEG 64  // Poisson(16): P(deg >= 64) ~ 1e-19 per node

#define GEMM1_BLOCKS ((N_NODES + 127) / 128)               // 782
#define DEG_EPT 8
#define DEG_BLOCKS ((N_EDGES + 256 * DEG_EPT - 1) / (256 * DEG_EPT))  // 782
#define FUSED_BLOCKS (GEMM1_BLOCKS + DEG_BLOCKS)           // 1564

#define NEG_BIG (-1e30f)
#define LDSP 132  // 128 + 4: bank stride 4 mod 32, keeps 16B alignment

// bf16 helpers (round-to-nearest-even)
__device__ __forceinline__ unsigned int f2bf_pack(float lo, float hi) {
  unsigned int ul = __float_as_uint(lo);
  unsigned int uh = __float_as_uint(hi);
  ul = (ul + 0x7FFFu + ((ul >> 16) & 1u)) >> 16;
  uh = (uh + 0x7FFFu + ((uh >> 16) & 1u)) >> 16;
  return ul | (uh << 16);
}
__device__ __forceinline__ float bf2f(unsigned short b) {
  return __uint_as_float(((unsigned int)b) << 16);
}

// ---------------- fused: layer-1 dual GEMM + one-pass padded-CSR scatter ----------------
// b&1==0 -> GEMM tile (782); else degree+scatter (782). KC=16 keeps LDS at
// 16.9 KB/block so the fabric-RMW-bound scatter gets more resident waves.

__global__ __launch_bounds__(256) void k_fused_gemm1_scatter(
    const float* __restrict__ x,
    const float* __restrict__ Wl, const float* __restrict__ bl,
    const float* __restrict__ Wr, const float* __restrict__ br,
    unsigned short* __restrict__ xlb, unsigned short* __restrict__ xrb,
    const int* __restrict__ src, const int* __restrict__ dst,
    int* __restrict__ deg, int* __restrict__ adjP) {
  constexpr int K = IN_CH;
  constexpr int KC = 16;
  constexpr int NCH = K / KC;  // 8
  __shared__ float xs[KC][LDSP];
  __shared__ float ws[KC][LDSP];

  int b = blockIdx.x;
  if (b & 1) {
    int db = b >> 1;
    int base = (db * 256 + threadIdx.x) * DEG_EPT;
    if (base + DEG_EPT <= N_EDGES) {
      int4 d4a = *(const int4*)&dst[base];
      int4 d4b = *(const int4*)&dst[base + 4];
      int4 s4a = *(const int4*)&src[base];
      int4 s4b = *(const int4*)&src[base + 4];
      int sl;
      sl = atomicAdd(&deg[d4a.x], 1); if (sl < MAX_DEG) adjP[d4a.x * MAX_DEG + sl] = s4a.x;
      sl = atomicAdd(&deg[d4a.y], 1); if (sl < MAX_DEG) adjP[d4a.y * MAX_DEG + sl] = s4a.y;
      sl = atomicAdd(&deg[d4a.z], 1); if (sl < MAX_DEG) adjP[d4a.z * MAX_DEG + sl] = s4a.z;
      sl = atomicAdd(&deg[d4a.w], 1); if (sl < MAX_DEG) adjP[d4a.w * MAX_DEG + sl] = s4a.w;
      sl = atomicAdd(&deg[d4b.x], 1); if (sl < MAX_DEG) adjP[d4b.x * MAX_DEG + sl] = s4b.x;
      sl = atomicAdd(&deg[d4b.y], 1); if (sl < MAX_DEG) adjP[d4b.y * MAX_DEG + sl] = s4b.y;
      sl = atomicAdd(&deg[d4b.z], 1); if (sl < MAX_DEG) adjP[d4b.z * MAX_DEG + sl] = s4b.z;
      sl = atomicAdd(&deg[d4b.w], 1); if (sl < MAX_DEG) adjP[d4b.w * MAX_DEG + sl] = s4b.w;
    } else {
      for (int e = base; e < N_EDGES; e++) {
        int d = dst[e];
        int sl = atomicAdd(&deg[d], 1);
        if (sl < MAX_DEG) adjP[d * MAX_DEG + sl] = src[e];
      }
    }
    return;
  }

  int tid = threadIdx.x;
  int tx = tid & 15;
  int ty = tid >> 4;
  int nb = (b >> 1) * 128;

  float acc[8][8];
  #pragma unroll
  for (int i = 0; i < 8; i++)
    #pragma unroll
    for (int j = 0; j < 8; j++) acc[i][j] = 0.f;

  for (int c = 0; c < NCH; c++) {
    int kc = c * KC;
    if (c) __syncthreads();
    #pragma unroll
    for (int j = 0; j < 2; j++) {
      int idx = tid + 256 * j;
      int node = idx >> 2, q = idx & 3;
      int gn = nb + node;
      float4 v = make_float4(0.f, 0.f, 0.f, 0.f);
      if (gn < N_NODES) v = *(const float4*)&x[(size_t)gn * K + kc + q * 4];
      xs[q * 4 + 0][node] = v.x;
      xs[q * 4 + 1][node] = v.y;
      xs[q * 4 + 2][node] = v.z;
      xs[q * 4 + 3][node] = v.w;
    }
    #pragma unroll
    for (int j = 0; j < 2; j++) {
      int idx = tid + 256 * j;
      int k = idx >> 5, cc = idx & 31;
      float4 v;
      if (cc < 16) v = *(const float4*)&Wl[(size_t)(kc + k) * 64 + cc * 4];
      else         v = *(const float4*)&Wr[(size_t)(kc + k) * 64 + (cc - 16) * 4];
      *(float4*)&ws[k][cc * 4] = v;
    }
    __syncthreads();

    #pragma unroll 4
    for (int k = 0; k < KC; k++) {
      float4 a0 = *(const float4*)&xs[k][ty * 8];
      float4 a1 = *(const float4*)&xs[k][ty * 8 + 4];
      float4 b0 = *(const float4*)&ws[k][tx * 8];
      float4 b1 = *(const float4*)&ws[k][tx * 8 + 4];
      float av[8] = {a0.x, a0.y, a0.z, a0.w, a1.x, a1.y, a1.z, a1.w};
      float bv[8] = {b0.x, b0.y, b0.z, b0.w, b1.x, b1.y, b1.z, b1.w};
      #pragma unroll
      for (int i = 0; i < 8; i++)
        #pragma unroll
        for (int j = 0; j < 8; j++)
          acc[i][j] = fmaf(av[i], bv[j], acc[i][j]);
    }
  }

  int f0 = tx * 8;
  float bb[8];
  #pragma unroll
  for (int j = 0; j < 8; j++)
    bb[j] = (f0 < 64) ? bl[f0 + j] : br[f0 - 64 + j];
  unsigned short* outp = (f0 < 64) ? xlb : xrb;
  int fo = (f0 < 64) ? f0 : f0 - 64;
  #pragma unroll
  for (int i = 0; i < 8; i++) {
    int node = nb + ty * 8 + i;
    if (node < N_NODES) {
      int4 o;
      o.x = (int)f2bf_pack(acc[i][0] + bb[0], acc[i][1] + bb[1]);
      o.y = (int)f2bf_pack(acc[i][2] + bb[2], acc[i][3] + bb[3]);
      o.z = (int)f2bf_pack(acc[i][4] + bb[4], acc[i][5] + bb[5]);
      o.w = (int)f2bf_pack(acc[i][6] + bb[6], acc[i][7] + bb[7]);
      *(int4*)&outp[(size_t)node * 64 + fo] = o;
    }
  }
}

// ---------------- layer-2 dual GEMM (fp32 in, bf16 out) ----------------

template <int K>
__global__ __launch_bounds__(256) void k_dual_gemm(
    const float* __restrict__ x,
    const float* __restrict__ Wl, const float* __restrict__ bl,
    const float* __restrict__ Wr, const float* __restrict__ br,
    unsigned short* __restrict__ xlb, unsigned short* __restrict__ xrb) {
  constexpr int KC = 32;
  constexpr int NCH = K / KC;
  __shared__ float xs[KC][LDSP];
  __shared__ float ws[KC][LDSP];

  int tid = threadIdx.x;
  int tx = tid & 15;
  int ty = tid >> 4;
  int nb = blockIdx.x * 128;

  float acc[8][8];
  #pragma unroll
  for (int i = 0; i < 8; i++)
    #pragma unroll
    for (int j = 0; j < 8; j++) acc[i][j] = 0.f;

  for (int c = 0; c < NCH; c++) {
    int kc = c * KC;
    if (c) __syncthreads();
    #pragma unroll
    for (int j = 0; j < 4; j++) {
      int idx = tid + 256 * j;
      int node = idx >> 3, q = idx & 7;
      int gn = nb + node;
      float4 v = make_float4(0.f, 0.f, 0.f, 0.f);
      if (gn < N_NODES) v = *(const float4*)&x[(size_t)gn * K + kc + q * 4];
      xs[q * 4 + 0][node] = v.x;
      xs[q * 4 + 1][node] = v.y;
      xs[q * 4 + 2][node] = v.z;
      xs[q * 4 + 3][node] = v.w;
    }
    #pragma unroll
    for (int j = 0; j < 4; j++) {
      int idx = tid + 256 * j;
      int k = idx >> 5, cc = idx & 31;
      float4 v;
      if (cc < 16) v = *(const float4*)&Wl[(size_t)(kc + k) * 64 + cc * 4];
      else         v = *(const float4*)&Wr[(size_t)(kc + k) * 64 + (cc - 16) * 4];
      *(float4*)&ws[k][cc * 4] = v;
    }
    __syncthreads();

    #pragma unroll 4
    for (int k = 0; k < KC; k++) {
      float4 a0 = *(const float4*)&xs[k][ty * 8];
      float4 a1 = *(const float4*)&xs[k][ty * 8 + 4];
      float4 b0 = *(const float4*)&ws[k][tx * 8];
      float4 b1 = *(const float4*)&ws[k][tx * 8 + 4];
      float av[8] = {a0.x, a0.y, a0.z, a0.w, a1.x, a1.y, a1.z, a1.w};
      float bv[8] = {b0.x, b0.y, b0.z, b0.w, b1.x, b1.y, b1.z, b1.w};
      #pragma unroll
      for (int i = 0; i < 8; i++)
        #pragma unroll
        for (int j = 0; j < 8; j++)
          acc[i][j] = fmaf(av[i], bv[j], acc[i][j]);
    }
  }

  int f0 = tx * 8;
  float bb[8];
  #pragma unroll
  for (int j = 0; j < 8; j++)
    bb[j] = (f0 < 64) ? bl[f0 + j] : br[f0 - 64 + j];
  unsigned short* outp = (f0 < 64) ? xlb : xrb;
  int fo = (f0 < 64) ? f0 : f0 - 64;
  #pragma unroll
  for (int i = 0; i < 8; i++) {
    int node = nb + ty * 8 + i;
    if (node < N_NODES) {
      int4 o;
      o.x = (int)f2bf_pack(acc[i][0] + bb[0], acc[i][1] + bb[1]);
      o.y = (int)f2bf_pack(acc[i][2] + bb[2], acc[i][3] + bb[3]);
      o.z = (int)f2bf_pack(acc[i][4] + bb[4], acc[i][5] + bb[5]);
      o.w = (int)f2bf_pack(acc[i][6] + bb[6], acc[i][7] + bb[7]);
      *(int4*)&outp[(size_t)node * 64 + fo] = o;
    }
  }
}

// ---------------- GATv2 layer (bf16 gathers, shfl-cached padded adjacency) ----------------
// R11-proven: lane = sub(2b)*16 + fg(4b), 2 edges/subgroup/iter, online softmax.

__global__ __launch_bounds__(256) void k_gat(
    const unsigned short* __restrict__ xlb, const unsigned short* __restrict__ xrb,
    const float* __restrict__ att, const float* __restrict__ bias,
    const int* __restrict__ deg, const int* __restrict__ adjP,
    float* __restrict__ out, int do_relu) {
  int wid = (blockIdx.x * 256 + threadIdx.x) >> 6;
  int lane = threadIdx.x & 63;
  if (wid >= N_NODES) return;
  int fg = lane & 15;
  int sub = lane >> 4;

  int degv = deg[wid];
  degv = (degv < MAX_DEG) ? degv : MAX_DEG;
  int L = degv + 1;  // + virtual self-loop at q=0

  int eidx = wid;
  if (lane < degv) eidx = adjP[(size_t)wid * MAX_DEG + lane];

  ushort4 xrr = *(const ushort4*)&xrb[(size_t)wid * 64 + fg * 4];
  float4 xr4;
  xr4.x = bf2f(xrr.x); xr4.y = bf2f(xrr.y); xr4.z = bf2f(xrr.z); xr4.w = bf2f(xrr.w);
  float4 att4 = *(const float4*)&att[fg * 4];

  float m = NEG_BIG, z = 0.f;
  float4 acc = make_float4(0.f, 0.f, 0.f, 0.f);

  for (int p0 = 0; p0 < L; p0 += 8) {
    int q0 = p0 + sub * 2;
    int q1 = q0 + 1;
    bool act0 = (q0 < L);
    bool act1 = (q1 < L);
    int idx0 = q0 - 1;
    int idx1 = q1 - 1;
    int sj0 = __shfl(eidx, idx0 & 63, 64);
    int sj1 = __shfl(eidx, idx1 & 63, 64);
    int j0 = (q0 == 0) ? wid : sj0;
    int j1 = sj1;
    ushort4 raw0 = make_ushort4(0, 0, 0, 0);
    ushort4 raw1 = make_ushort4(0, 0, 0, 0);
    if (act0) raw0 = *(const ushort4*)&xlb[(size_t)j0 * 64 + fg * 4];
    if (act1) raw1 = *(const ushort4*)&xlb[(size_t)j1 * 64 + fg * 4];
    float4 v0, v1;
    v0.x = bf2f(raw0.x); v0.y = bf2f(raw0.y); v0.z = bf2f(raw0.z); v0.w = bf2f(raw0.w);
    v1.x = bf2f(raw1.x); v1.y = bf2f(raw1.y); v1.z = bf2f(raw1.z); v1.w = bf2f(raw1.w);

    float ax, ay, az, aw;
    ax = v0.x + xr4.x; ax = (ax >= 0.f) ? ax : NEG_SLOPE * ax;
    ay = v0.y + xr4.y; ay = (ay >= 0.f) ? ay : NEG_SLOPE * ay;
    az = v0.z + xr4.z; az = (az >= 0.f) ? az : NEG_SLOPE * az;
    aw = v0.w + xr4.w; aw = (aw >= 0.f) ? aw : NEG_SLOPE * aw;
    float s0 = fmaf(ax, att4.x, fmaf(ay, att4.y, fmaf(az, att4.z, aw * att4.w)));
    ax = v1.x + xr4.x; ax = (ax >= 0.f) ? ax : NEG_SLOPE * ax;
    ay = v1.y + xr4.y; ay = (ay >= 0.f) ? ay : NEG_SLOPE * ay;
    az = v1.z + xr4.z; az = (az >= 0.f) ? az : NEG_SLOPE * az;
    aw = v1.w + xr4.w; aw = (aw >= 0.f) ? aw : NEG_SLOPE * aw;
    float s1 = fmaf(ax, att4.x, fmaf(ay, att4.y, fmaf(az, att4.z, aw * att4.w)));
    #pragma unroll
    for (int o = 1; o <= 8; o <<= 1) {
      s0 += __shfl_xor(s0, o, 64);
      s1 += __shfl_xor(s1, o, 64);
    }
    float e0 = act0 ? s0 : NEG_BIG;
    float e1 = act1 ? s1 : NEG_BIG;

    float nm = fmaxf(m, fmaxf(e0, e1));
    float sc = __expf(m - nm);
    float w0 = __expf(e0 - nm);
    float w1 = __expf(e1 - nm);
    z = fmaf(z, sc, w0 + w1);
    acc.x = fmaf(acc.x, sc, fmaf(w0, v0.x, w1 * v1.x));
    acc.y = fmaf(acc.y, sc, fmaf(w0, v0.y, w1 * v1.y));
    acc.z = fmaf(acc.z, sc, fmaf(w0, v0.z, w1 * v1.z));
    acc.w = fmaf(acc.w, sc, fmaf(w0, v0.w, w1 * v1.w));
    m = nm;
  }

  #pragma unroll
  for (int o = 16; o <= 32; o <<= 1) {
    float m2 = __shfl_xor(m, o, 64);
    float z2 = __shfl_xor(z, o, 64);
    float a0 = __shfl_xor(acc.x, o, 64);
    float a1 = __shfl_xor(acc.y, o, 64);
    float a2 = __shfl_xor(acc.z, o, 64);
    float a3 = __shfl_xor(acc.w, o, 64);
    float nm = fmaxf(m, m2);
    float s1 = __expf(m - nm);
    float s2 = __expf(m2 - nm);
    z = z * s1 + z2 * s2;
    acc.x = acc.x * s1 + a0 * s2;
    acc.y = acc.y * s1 + a1 * s2;
    acc.z = acc.z * s1 + a2 * s2;
    acc.w = acc.w * s1 + a3 * s2;
    m = nm;
  }

  if (sub == 0) {
    float4 b4 = *(const float4*)&bias[fg * 4];
    float inv = 1.f / z;
    float4 r;
    r.x = acc.x * inv + b4.x;
    r.y = acc.y * inv + b4.y;
    r.z = acc.z * inv + b4.z;
    r.w = acc.w * inv + b4.w;
    if (do_relu) {
      r.x = fmaxf(r.x, 0.f); r.y = fmaxf(r.y, 0.f);
      r.z = fmaxf(r.z, 0.f); r.w = fmaxf(r.w, 0.f);
    }
    *(float4*)&out[(size_t)wid * 64 + fg * 4] = r;
  }
}

// ---------------- global mean pool (batch is sorted) ----------------

__device__ __forceinline__ int lower_bound_batch(const int* __restrict__ b, int key) {
  int lo = 0, hi = N_NODES;
  while (lo < hi) {
    int mid = (lo + hi) >> 1;
    if (b[mid] < key) lo = mid + 1; else hi = mid;
  }
  return lo;
}

__global__ void k_pool(const float* __restrict__ h, const int* __restrict__ batch,
                       float* __restrict__ gmean) {
  __shared__ int s_range[2];
  __shared__ float red[256];
  int g = blockIdx.x, t = threadIdx.x;
  if (t == 0) s_range[0] = lower_bound_batch(batch, g);
  if (t == 1) s_range[1] = lower_bound_batch(batch, g + 1);
  __syncthreads();
  int lo = s_range[0], hi = s_range[1];
  int f = t & 63, sub = t >> 6;
  float acc = 0.f;
  for (int n = lo + sub; n < hi; n += 4) acc += h[n * 64 + f];
  red[t] = acc;
  __syncthreads();
  if (sub == 0) {
    float s = red[f] + red[64 + f] + red[128 + f] + red[192 + f];
    int cnt = hi - lo;
    if (cnt < 1) cnt = 1;
    gmean[g * 64 + f] = s / (float)cnt;
  }
}

// ---------------- MLP head (separate small kernels) ----------------

__global__ void k_head1(const float* __restrict__ gmean, const float* __restrict__ W,
                        const float* __restrict__ b, float* __restrict__ y) {
  int idx = blockIdx.x * 256 + threadIdx.x;
  if (idx >= N_GRAPHS * 64) return;
  int gi = idx >> 6, f = idx & 63;
  float acc = b[f];
  #pragma unroll 8
  for (int k = 0; k < 64; k++) acc = fmaf(gmean[gi * 64 + k], W[k * 64 + f], acc);
  y[idx] = acc;
}

__global__ void k_bnstats(const float* __restrict__ y, float* __restrict__ mu,
                          float* __restrict__ rstd) {
  __shared__ float red_s[256], red_ss[256];
  int t = threadIdx.x;
  int f = t & 63, grp = t >> 6;
  float s = 0.f, ss = 0.f;
  for (int g = grp; g < N_GRAPHS; g += 4) {
    float v = y[g * 64 + f];
    s += v;
    ss += v * v;
  }
  red_s[t] = s;
  red_ss[t] = ss;
  __syncthreads();
  if (t < 64) {
    s = red_s[t] + red_s[64 + t] + red_s[128 + t] + red_s[192 + t];
    ss = red_ss[t] + red_ss[64 + t] + red_ss[128 + t] + red_ss[192 + t];
    float m = s / (float)N_GRAPHS;
    float var = ss / (float)N_GRAPHS - m * m;
    mu[t] = m;
    rstd[t] = rsqrtf(var + 1e-5f);
  }
}

__global__ void k_head2(const float* __restrict__ y, const float* __restrict__ gamma,
                        const float* __restrict__ beta, const float* __restrict__ mu,
                        const float* __restrict__ rstd, const float* __restrict__ W2,
                        const float* __restrict__ b2, float* __restrict__ out) {
  int idx = blockIdx.x * 256 + threadIdx.x;
  if (idx >= N_GRAPHS * OUT_CH) return;
  int gi = idx >> 4, o = idx & 15;
  float acc = b2[o];
  #pragma unroll
  for (int k = 0; k < 64; k++) {
    float v = y[gi * 64 + k];
    v = gamma[k] * (v - mu[k]) * rstd[k] + beta[k];
    v = fmaxf(v, 0.f);
    acc = fmaf(v, W2[k * OUT_CH + o], acc);
  }
  float mx = acc;
  #pragma unroll
  for (int w = 8; w > 0; w >>= 1) mx = fmaxf(mx, __shfl_xor(mx, w, 16));
  float ex = __expf(acc - mx);
  float s = ex;
  #pragma unroll
  for (int w = 8; w > 0; w >>= 1) s += __shfl_xor(s, w, 16);
  out[idx] = acc - mx - __logf(s);
}

// ---------------- launcher ----------------
// ws budget (proven): deg 0.4 + adjP 25.6 + xlb 12.8 + xrb 12.8 + h 25.6
// + small ~0.3 = ~77.5 MB.

extern "C" void kernel_launch(void* const* d_in, const int* in_sizes, int n_in,
                              void* d_out, int out_size, void* d_ws, size_t ws_size,
                              hipStream_t stream) {
  const float* x      = (const float*)d_in[0];
  const int*   edge   = (const int*)d_in[1];
  const int*   batch  = (const int*)d_in[2];
  const float* W_l1   = (const float*)d_in[3];
  const float* b_l1   = (const float*)d_in[4];
  const float* W_r1   = (const float*)d_in[5];
  const float* b_r1   = (const float*)d_in[6];
  const float* att1   = (const float*)d_in[7];
  const float* bias1  = (const float*)d_in[8];
  const float* W_l2   = (const float*)d_in[9];
  const float* b_l2   = (const float*)d_in[10];
  const float* W_r2   = (const float*)d_in[11];
  const float* b_r2   = (const float*)d_in[12];
  const float* att2   = (const float*)d_in[13];
  const float* bias2  = (const float*)d_in[14];
  const float* W_fc1  = (const float*)d_in[15];
  const float* b_fc1  = (const float*)d_in[16];
  const float* gamma  = (const float*)d_in[17];
  const float* beta   = (const float*)d_in[18];
  const float* W_fc2  = (const float*)d_in[19];
  const float* b_fc2  = (const float*)d_in[20];

  const int* src = edge;
  const int* dst = edge + N_EDGES;

  char* ws = (char*)d_ws;
  size_t off = 0;
  auto alloc = [&](size_t bytes) -> void* {
    off = (off + 255) & ~(size_t)255;
    void* p = ws + off;
    off += bytes;
    return p;
  };
  int* deg      = (int*)alloc((size_t)N_NODES * 4);
  int* adjP     = (int*)alloc((size_t)N_NODES * MAX_DEG * 4);
  unsigned short* xlb = (unsigned short*)alloc((size_t)N_NODES * HID * 2);
  unsigned short* xrb = (unsigned short*)alloc((size_t)N_NODES * HID * 2);
  float* h      = (float*)alloc((size_t)N_NODES * HID * 4);
  float* gmean  = (float*)alloc((size_t)N_GRAPHS * HID * 4);
  float* y      = (float*)alloc((size_t)N_GRAPHS * HID * 4);
  float* mu     = (float*)alloc(64 * 4);
  float* rstd   = (float*)alloc(64 * 4);

  hipMemsetAsync(deg, 0, (size_t)N_NODES * 4, stream);

  k_fused_gemm1_scatter<<<FUSED_BLOCKS, 256, 0, stream>>>(
      x, W_l1, b_l1, W_r1, b_r1, xlb, xrb, src, dst, deg, adjP);

  k_gat<<<(N_NODES + 3) / 4, 256, 0, stream>>>(xlb, xrb, att1, bias1, deg, adjP, h, 1);
  k_dual_gemm<HID><<<(N_NODES + 127) / 128, 256, 0, stream>>>(h, W_l2, b_l2, W_r2, b_r2, xlb, xrb);
  k_gat<<<(N_NODES + 3) / 4, 256, 0, stream>>>(xlb, xrb, att2, bias2, deg, adjP, h, 0);

  k_pool<<<N_GRAPHS, 256, 0, stream>>>(h, batch, gmean);
  k_head1<<<(N_GRAPHS * 64 + 255) / 256, 256, 0, stream>>>(gmean, W_fc1, b_fc1, y);
  k_bnstats<<<1, 256, 0, stream>>>(y, mu, rstd);
  k_head2<<<(N_GRAPHS * OUT_CH + 255) / 256, 256, 0, stream>>>(y, gamma, beta, mu, rstd,
                                                               W_fc2, b_fc2, (float*)d_out);
}